// Round 10
// baseline (194.893 us; speedup 1.0000x reference)
//
#include <hip/hip_runtime.h>

#define NSAMP 4096
#define NITER 200

// DPP fmac/mul: src0 (resid register) read through row_ror:t.
#define DPL(op, acc, rr, mm, rot) \
  op " " acc ", " rr ", " mm " row_ror:" #rot " row_mask:0xf bank_mask:0xf\n\t"

// ---------------------------------------------------------------------------
// R10 = R9's fusion + R8's proven d=48 loop + conflict-free padded Mperm.
//  - Each block redundantly computes the Woodbury inverse in its own LDS
//    (deletes the separate setup launch; R9 measured the win).
//  - Loop: 48 elements on DPP (stages 0-2: r, r^16, r^48 via 1 ds_swizzle +
//    1 ds_bpermute), 16 elements (xor-32 block) via 4 staggered ds_read_b128
//    + 8 v_pk_fma_f32. 9 DS-instr/iter, 0 loop conflicts (R8 measured).
//  - Mperm stored in LDS with ROW STRIDE 65 floats: prologue ds_read_b128
//    word addr = 65*lane + 4q === lane + 4q (mod 32) -> 2 lanes/bank (free).
//    R9's stride-64 layout put all 64 lanes in 4 banks (~16-way, ~3-4M
//    conflict cycles one-time = the R9 regression).
// LDS pool: 40208 B -> 4 blocks/CU preserved.
// ---------------------------------------------------------------------------
__global__ __launch_bounds__(256)
void admm_fused(const float* __restrict__ target, const float* __restrict__ A,
                const float* __restrict__ x0, float* __restrict__ out) {
  __shared__ __align__(16) char smem[40208];
  float (*Mfull)[64] = (float(*)[64])(smem);          // 16384
  float* Mperm       = (float*)(smem + 16384);        // 64*65*4 = 16640
  float (*rbuf)[64]  = (float(*)[64])(smem + 33024);  // 1024 (aliases lamr)
  double* lamr       = (double*)(smem + 33024);       // 512, dead before rbuf
  float* binv        = (float*)(smem + 34048);        // 256
  float (*P)[64]     = (float(*)[64])(smem + 34304);  // 2304
  float (*Q)[64]     = (float(*)[64])(smem + 36608);  // 2304
  double (*W)[18]    = (double(*)[18])(smem + 38912); // 1296

  const int tid = threadIdx.x;
  const int wid = tid >> 6;
  const int lane = tid & 63;
  const int s = blockIdx.x * 4 + wid;
  const double TWO_PI = 6.283185307179586476925286766559;

  // ---- setup phase (per block, ~3us) ----
  double cb = 0.0;
  if (tid < 64) {
    cb = cos(TWO_PI * (double)tid / 64.0);
    lamr[tid] = 1.0 / (9.0 - 4.0 * cb);
  }
  __syncthreads();
  if (tid < 64) {
    double cm1 = 1.0, c0 = cb;
    double acc = lamr[0] + cb * lamr[1];
#pragma unroll 16
    for (int m = 2; m < 64; ++m) {
      double c = 2.0 * cb * c0 - cm1;
      cm1 = c0;
      c0 = c;
      acc += c * lamr[m];
    }
    binv[tid] = (float)(acc / 64.0);
  }
  __syncthreads();

  for (int e = tid; e < 9 * 64; e += 256) {
    int m = e >> 6, i = e & 63;
    double acc = 0.0;
#pragma unroll 16
    for (int k = 0; k < 64; ++k)
      acc += (double)A[m * 64 + k] * (double)binv[(k - i) & 63];
    P[m][i] = (float)acc;
  }
  __syncthreads();

  if (tid < 81) {
    int m = tid / 9, n = tid % 9;
    double acc = (m == n) ? 1.0 : 0.0;
#pragma unroll 16
    for (int i = 0; i < 64; ++i)
      acc += (double)P[m][i] * (double)A[n * 64 + i];
    W[m][n] = acc;
    W[m][n + 9] = (m == n) ? 1.0 : 0.0;
  }
  __syncthreads();

  {
    const int r9 = tid / 18, c9 = tid % 18;
    const bool act = (tid < 162);
    for (int k = 0; k < 9; ++k) {
      double pv = 1.0, f = 0.0, wkc = 0.0;
      if (act) {
        pv = W[k][k];
        f = W[r9][k];
        wkc = W[k][c9];
      }
      __syncthreads();
      if (act) {
        double nk = wkc / pv;
        W[r9][c9] = (r9 == k) ? nk : fma(-f, nk, W[r9][c9]);
      }
      __syncthreads();
    }
  }

  for (int e = tid; e < 9 * 64; e += 256) {
    int m = e >> 6, j = e & 63;
    double acc = 0.0;
#pragma unroll
    for (int n = 0; n < 9; ++n) acc += W[m][n + 9] * (double)P[n][j];
    Q[m][j] = (float)acc;
  }
  __syncthreads();

  for (int e = tid; e < 64 * 64; e += 256) {
    int i = e >> 6, j = e & 63;
    float acc = binv[(i - j) & 63];
#pragma unroll
    for (int m = 0; m < 9; ++m) acc = fmaf(-P[m][i], Q[m][j], acc);
    Mfull[i][j] = acc;
  }
  __syncthreads();

  // probe DPP row_ror direction (register-only, per wave)
  int dpp1;
  asm volatile(
      "s_nop 4\n\t"
      "v_mov_b32_dpp %0, %1 row_ror:1 row_mask:0xf bank_mask:0xf\n\t"
      "s_nop 4"
      : "=v"(dpp1)
      : "v"(lane));
  const int dir = (__builtin_amdgcn_readfirstlane(dpp1) == 1) ? 1 : -1;

  // emit permuted M (R8 mapping: 48 DPP cols + 16 staggered-quad cols),
  // padded row stride 65.
  for (int e = tid; e < 64 * 64; e += 256) {
    int li = e >> 6, k = e & 63;
    int j;
    if (k < 48) {
      int st = k >> 4, t = k & 15;
      int xs = (st == 0) ? 0 : (st == 1 ? 16 : 48);
      int q = (li & 48) | (((li & 15) + dir * t + 16) & 15);
      j = q ^ xs;
    } else {
      int t = (k - 48) >> 2, ee = k & 3;
      j = ((li & 48) ^ 32) + 4 * ((((li >> 4) & 3) + t) & 3) + ee;
    }
    Mperm[li * 65 + k] = Mfull[li][j];
  }
  __syncthreads();

  // ---- ATb = (target_s @ A^T) @ A via 9 wave-reductions ----
  float t = target[s * 64 + lane];
  float atbv = 0.f;
#pragma unroll
  for (int m = 0; m < 9; ++m) {
    float a = A[m * 64 + lane];
    float p = t * a;
#pragma unroll
    for (int off = 32; off; off >>= 1) p += __shfl_xor(p, off, 64);
    atbv = fmaf(a, p, atbv);
  }

  unsigned int mprm = (unsigned int)(uintptr_t)(Mperm + lane * 65);
  unsigned int rb = (unsigned int)(uintptr_t)(&rbuf[wid][0]);
  unsigned int a_w = rb + lane * 4;
  unsigned int a_nxt = ((lane + 1) & 63) * 4;  // bpermute: pull lane+1
  unsigned int a_x32 = (lane ^ 32) * 4;        // bpermute: pull lane^32
  // stage-3 read addresses: xor-32 block, quad staggered by group (R8)
  unsigned int g = (lane >> 4) & 3;
  unsigned int base3 = rb + (((lane & 48) ^ 32) << 2);
  unsigned int aq0 = base3 + (((g + 0) & 3) << 4);
  unsigned int aq1 = base3 + (((g + 1) & 3) << 4);
  unsigned int aq2 = base3 + (((g + 2) & 3) << 4);
  unsigned int aq3 = base3 + (((g + 3) & 3) << 4);
  float xin = x0[s * 64 + lane];
  float xout;
  int cnt_s;
  const int smask = 0x7fffffff;
  const float sthr = 5e-5f, sc02 = 0.2f, sc5 = 5.0f;

  asm volatile(
      "s_mov_b32 m0, -1\n\t"
      // --- M' row from LDS (stride 260B, conflict-free) into v64-v127 ---
      "ds_read_b128 v[64:67],   %[mprm]\n\t"
      "ds_read_b128 v[68:71],   %[mprm] offset:16\n\t"
      "ds_read_b128 v[72:75],   %[mprm] offset:32\n\t"
      "ds_read_b128 v[76:79],   %[mprm] offset:48\n\t"
      "ds_read_b128 v[80:83],   %[mprm] offset:64\n\t"
      "ds_read_b128 v[84:87],   %[mprm] offset:80\n\t"
      "ds_read_b128 v[88:91],   %[mprm] offset:96\n\t"
      "ds_read_b128 v[92:95],   %[mprm] offset:112\n\t"
      "ds_read_b128 v[96:99],   %[mprm] offset:128\n\t"
      "ds_read_b128 v[100:103], %[mprm] offset:144\n\t"
      "ds_read_b128 v[104:107], %[mprm] offset:160\n\t"
      "ds_read_b128 v[108:111], %[mprm] offset:176\n\t"
      "ds_read_b128 v[112:115], %[mprm] offset:192\n\t"
      "ds_read_b128 v[116:119], %[mprm] offset:208\n\t"
      "ds_read_b128 v[120:123], %[mprm] offset:224\n\t"
      "ds_read_b128 v[124:127], %[mprm] offset:240\n\t"
      // --- init: v32=x v33=eta v34=tau v35=Dx v36=atb ---
      "v_mov_b32 v32, %[xin]\n\t"
      "v_mov_b32 v36, %[atb]\n\t"
      "v_mov_b32 v33, 0\n\t"
      "v_mov_b32 v34, 0\n\t"
      "ds_bpermute_b32 v45, %[anx], v32\n\t"
      "s_waitcnt lgkmcnt(0)\n\t"
      "v_sub_f32 v35, v45, v32\n\t"
      "s_movk_i32 %[cnt], 200\n\t"
      "1:\n\t"
      // u = copysign(max(|0.5*eta+Dx|-thr,0), .) -> v42
      "v_fma_f32 v40, 0.5, v33, v35\n\t"
      "v_and_b32 v41, %[msk], v40\n\t"
      "v_subrev_f32 v41, %[thr], v41\n\t"
      "v_max_f32 v41, 0, v41\n\t"
      "v_bfi_b32 v42, %[msk], v41, v40\n\t"
      // w = max(0.2*tau + x, 0) -> v43
      "v_fma_f32 v43, %[c02], v34, v32\n\t"
      "v_max_f32 v43, 0, v43\n\t"
      // tv = 2u - eta -> v40 ; ts = tv[lane+1] -> v45
      "v_fma_f32 v40, 2.0, v42, -v33\n\t"
      "ds_bpermute_b32 v45, %[anx], v40\n\t"
      // resid = 5w + atb - tau - tv + ts -> v44
      "v_fma_f32 v44, %[c5], v43, v36\n\t"
      "v_sub_f32 v44, v44, v34\n\t"
      "v_sub_f32 v44, v44, v40\n\t"
      "s_waitcnt lgkmcnt(0)\n\t"
      "v_add_f32 v44, v44, v45\n\t"
      // stage-1 source (xor16), resid store, stage-3 quad reads (staggered)
      "ds_swizzle_b32 v45, v44 offset:0x401F\n\t"
      "ds_write_b32 %[aw], v44\n\t"
      "ds_read_b128 v[48:51], %[aq0]\n\t"
      "ds_read_b128 v[52:55], %[aq1]\n\t"
      "ds_read_b128 v[56:59], %[aq2]\n\t"
      "ds_read_b128 v[60:63], %[aq3]\n\t"
      // ---- stage 0: r=v44, m=v64-79 (reads fly underneath) ----
      "v_mul_f32 v37, v44, v64\n\t"
      DPL("v_mul_f32",  "v38", "v44", "v65", 1)
      DPL("v_mul_f32",  "v39", "v44", "v66", 2)
      DPL("v_mul_f32",  "v40", "v44", "v67", 3)
      DPL("v_fmac_f32", "v37", "v44", "v68", 4)
      DPL("v_fmac_f32", "v38", "v44", "v69", 5)
      DPL("v_fmac_f32", "v39", "v44", "v70", 6)
      DPL("v_fmac_f32", "v40", "v44", "v71", 7)
      DPL("v_fmac_f32", "v37", "v44", "v72", 8)
      DPL("v_fmac_f32", "v38", "v44", "v73", 9)
      DPL("v_fmac_f32", "v39", "v44", "v74", 10)
      DPL("v_fmac_f32", "v40", "v44", "v75", 11)
      DPL("v_fmac_f32", "v37", "v44", "v76", 12)
      DPL("v_fmac_f32", "v38", "v44", "v77", 13)
      DPL("v_fmac_f32", "v39", "v44", "v78", 14)
      DPL("v_fmac_f32", "v40", "v44", "v79", 15)
      // swizzle (oldest of 6 outstanding) done when <=5 remain
      "s_waitcnt lgkmcnt(5)\n\t"
      "ds_bpermute_b32 v46, %[a32], v45\n\t"
      "s_nop 1\n\t"
      // ---- stage 1: r=v45 (xor16), m=v80-95 ----
      "v_fmac_f32 v37, v45, v80\n\t"
      DPL("v_fmac_f32", "v38", "v45", "v81", 1)
      DPL("v_fmac_f32", "v39", "v45", "v82", 2)
      DPL("v_fmac_f32", "v40", "v45", "v83", 3)
      DPL("v_fmac_f32", "v37", "v45", "v84", 4)
      DPL("v_fmac_f32", "v38", "v45", "v85", 5)
      DPL("v_fmac_f32", "v39", "v45", "v86", 6)
      DPL("v_fmac_f32", "v40", "v45", "v87", 7)
      DPL("v_fmac_f32", "v37", "v45", "v88", 8)
      DPL("v_fmac_f32", "v38", "v45", "v89", 9)
      DPL("v_fmac_f32", "v39", "v45", "v90", 10)
      DPL("v_fmac_f32", "v40", "v45", "v91", 11)
      DPL("v_fmac_f32", "v37", "v45", "v92", 12)
      DPL("v_fmac_f32", "v38", "v45", "v93", 13)
      DPL("v_fmac_f32", "v39", "v45", "v94", 14)
      DPL("v_fmac_f32", "v40", "v45", "v95", 15)
      // all DS (write, 4 reads, bpermute) drained; quads + v46 ready
      "s_waitcnt lgkmcnt(0)\n\t"
      "s_nop 1\n\t"
      // ---- stage 2: r=v46 (xor48), m=v96-111 ----
      "v_fmac_f32 v37, v46, v96\n\t"
      DPL("v_fmac_f32", "v38", "v46", "v97", 1)
      DPL("v_fmac_f32", "v39", "v46", "v98", 2)
      DPL("v_fmac_f32", "v40", "v46", "v99", 3)
      DPL("v_fmac_f32", "v37", "v46", "v100", 4)
      DPL("v_fmac_f32", "v38", "v46", "v101", 5)
      DPL("v_fmac_f32", "v39", "v46", "v102", 6)
      DPL("v_fmac_f32", "v40", "v46", "v103", 7)
      DPL("v_fmac_f32", "v37", "v46", "v104", 8)
      DPL("v_fmac_f32", "v38", "v46", "v105", 9)
      DPL("v_fmac_f32", "v39", "v46", "v106", 10)
      DPL("v_fmac_f32", "v40", "v46", "v107", 11)
      DPL("v_fmac_f32", "v37", "v46", "v108", 12)
      DPL("v_fmac_f32", "v38", "v46", "v109", 13)
      DPL("v_fmac_f32", "v39", "v46", "v110", 14)
      DPL("v_fmac_f32", "v40", "v46", "v111", 15)
      // ---- stage 3: xor-32 block via staggered LDS quads, packed fp32 ----
      "v_pk_mul_f32 v[44:45], v[112:113], v[48:49]\n\t"
      "v_pk_mul_f32 v[46:47], v[114:115], v[50:51]\n\t"
      "v_pk_fma_f32 v[44:45], v[116:117], v[52:53], v[44:45]\n\t"
      "v_pk_fma_f32 v[46:47], v[118:119], v[54:55], v[46:47]\n\t"
      "v_pk_fma_f32 v[44:45], v[120:121], v[56:57], v[44:45]\n\t"
      "v_pk_fma_f32 v[46:47], v[122:123], v[58:59], v[46:47]\n\t"
      "v_pk_fma_f32 v[44:45], v[124:125], v[60:61], v[44:45]\n\t"
      "v_pk_fma_f32 v[46:47], v[126:127], v[62:63], v[46:47]\n\t"
      // combine -> x_new in v32
      "v_add_f32 v37, v37, v38\n\t"
      "v_add_f32 v39, v39, v40\n\t"
      "v_pk_add_f32 v[44:45], v[44:45], v[46:47]\n\t"
      "v_add_f32 v37, v37, v39\n\t"
      "v_add_f32 v44, v44, v45\n\t"
      "v_add_f32 v32, v37, v44\n\t"
      // Dx = x[lane+1] - x ; duals (tau update overlaps bpermute)
      "ds_bpermute_b32 v45, %[anx], v32\n\t"
      "v_sub_f32 v41, v32, v43\n\t"
      "v_fma_f32 v34, %[c5], v41, v34\n\t"
      "s_waitcnt lgkmcnt(0)\n\t"
      "v_sub_f32 v35, v45, v32\n\t"
      "v_sub_f32 v41, v35, v42\n\t"
      "v_fma_f32 v33, 2.0, v41, v33\n\t"
      "s_sub_u32 %[cnt], %[cnt], 1\n\t"
      "s_cmp_lg_u32 %[cnt], 0\n\t"
      "s_cbranch_scc1 1b\n\t"
      "v_mov_b32 %[xout], v32\n\t"
      : [xout] "=v"(xout), [cnt] "=&s"(cnt_s)
      : [mprm] "v"(mprm), [aw] "v"(a_w), [anx] "v"(a_nxt), [a32] "v"(a_x32),
        [aq0] "v"(aq0), [aq1] "v"(aq1), [aq2] "v"(aq2), [aq3] "v"(aq3),
        [xin] "v"(xin), [atb] "v"(atbv),
        [msk] "s"(smask), [thr] "s"(sthr), [c02] "s"(sc02), [c5] "s"(sc5)
      : "memory", "scc",
        "v32","v33","v34","v35","v36","v37","v38","v39","v40","v41","v42","v43",
        "v44","v45","v46","v47","v48","v49","v50","v51","v52","v53","v54","v55",
        "v56","v57","v58","v59","v60","v61","v62","v63","v64","v65","v66","v67",
        "v68","v69","v70","v71","v72","v73","v74","v75","v76","v77","v78","v79",
        "v80","v81","v82","v83","v84","v85","v86","v87","v88","v89","v90","v91",
        "v92","v93","v94","v95","v96","v97","v98","v99","v100","v101","v102",
        "v103","v104","v105","v106","v107","v108","v109","v110","v111","v112",
        "v113","v114","v115","v116","v117","v118","v119","v120","v121","v122",
        "v123","v124","v125","v126","v127");

  out[s * 64 + lane] = xout;
}

extern "C" void kernel_launch(void* const* d_in, const int* in_sizes, int n_in,
                              void* d_out, int out_size, void* d_ws, size_t ws_size,
                              hipStream_t stream) {
  const float* target = (const float*)d_in[0];  // (4096, 64)
  const float* A = (const float*)d_in[1];       // (9, 64)
  const float* x0 = (const float*)d_in[2];      // (4096, 64)
  float* out = (float*)d_out;                   // (4096, 64)

  admm_fused<<<NSAMP / 4, 256, 0, stream>>>(target, A, x0, out);
}